// Round 8
// baseline (1314.846 us; speedup 1.0000x reference)
//
#include <hip/hip_runtime.h>
#include <hip/hip_bf16.h>
#include <stdint.h>

// LoRALinear fused: y = x @ (W + lora_A @ lora_B)^T + bias
// W_eff = W + A@B folded; x, W_eff split to bf16 hi+lo; 3-segment bf16 MFMA
// GEMM (hi*hi + lo*hi + hi*lo), fp32 accumulate. K_eff = 3*4096 = 12288.
// R8 GEMM: LDS-traffic reduction. A: LDS-staged (4x wave reuse), XOR-swizzled,
// double-buffered (64 KiB total). B: NEVER in LDS -- 8 fragments/wave/tile
// loaded global->VGPR, double-buffered one tile ahead (Bx/By static names).
// LDS/tile: 256KB -> 160KB (off critical path); MFMA pipe becomes binding.
// One barrier + one vmcnt(0) per tile; setprio on MFMA clusters.

typedef unsigned short u16;
typedef __attribute__((ext_vector_type(8))) u16 u16x8;
typedef __attribute__((ext_vector_type(4))) u16 u16x4;
typedef __attribute__((ext_vector_type(8))) __bf16 bf16x8;
typedef __attribute__((ext_vector_type(4))) float f32x4;

#define IN_F 4096
#define OUT_F 4096
#define MTOT 8192  // B*S
#define RANK 16
#define NT64 192  // 3 segments * (4096/64) K-tiles

__device__ __forceinline__ u16 f2bf(float f) {
  unsigned u = __float_as_uint(f);
  unsigned r = u + 0x7FFFu + ((u >> 16) & 1u);
  return (u16)(r >> 16);
}
__device__ __forceinline__ float bf2f(u16 h) {
  return __uint_as_float(((unsigned)h) << 16);
}

// ---------------- fused prep (R7 version, unchanged) ----------------
__global__ __launch_bounds__(256) void prep_kernel(
    const float* __restrict__ x, const float* __restrict__ W,
    const float* __restrict__ lA, const float* __restrict__ lB,
    u16* __restrict__ xhi, u16* __restrict__ xlo, u16* __restrict__ whi,
    u16* __restrict__ wlo) {
  const int t = threadIdx.x;
  if (blockIdx.x < 3072) {
    const int n4 = (MTOT * IN_F) / 4;
    int idx = blockIdx.x * 256 + t;
    for (; idx < n4; idx += 3072 * 256) {
      float4 v = ((const float4*)x)[idx];
      u16x4 h, l;
      h.x = f2bf(v.x); l.x = f2bf(v.x - bf2f(h.x));
      h.y = f2bf(v.y); l.y = f2bf(v.y - bf2f(h.y));
      h.z = f2bf(v.z); l.z = f2bf(v.z - bf2f(h.z));
      h.w = f2bf(v.w); l.w = f2bf(v.w - bf2f(h.w));
      ((u16x4*)xhi)[idx] = h;
      ((u16x4*)xlo)[idx] = l;
    }
  } else {
    const int bw = blockIdx.x - 3072;
    const int strip = bw & 31;
    const int og = bw >> 5;
    const int i4 = strip * 32 + (t & 31);
    float4 lbr[RANK];
#pragma unroll
    for (int r = 0; r < RANK; ++r)
      lbr[r] = ((const float4*)lB)[r * (IN_F / 4) + i4];
#pragma unroll 1
    for (int j = 0; j < 16; ++j) {
      const int o = og * 128 + (t >> 5) + 8 * j;
      float a[RANK];
#pragma unroll
      for (int q = 0; q < 4; ++q) {
        float4 av = ((const float4*)lA)[o * (RANK / 4) + q];
        a[q * 4 + 0] = av.x; a[q * 4 + 1] = av.y;
        a[q * 4 + 2] = av.z; a[q * 4 + 3] = av.w;
      }
      float4 acc = ((const float4*)W)[o * (IN_F / 4) + i4];
#pragma unroll
      for (int r = 0; r < RANK; ++r) {
        acc.x += a[r] * lbr[r].x; acc.y += a[r] * lbr[r].y;
        acc.z += a[r] * lbr[r].z; acc.w += a[r] * lbr[r].w;
      }
      u16x4 h, l;
      h.x = f2bf(acc.x); l.x = f2bf(acc.x - bf2f(h.x));
      h.y = f2bf(acc.y); l.y = f2bf(acc.y - bf2f(h.y));
      h.z = f2bf(acc.z); l.z = f2bf(acc.z - bf2f(h.z));
      h.w = f2bf(acc.w); l.w = f2bf(acc.w - bf2f(h.w));
      ((u16x4*)whi)[o * (IN_F / 4) + i4] = h;
      ((u16x4*)wlo)[o * (IN_F / 4) + i4] = l;
    }
  }
}

// ---------------- main: A-in-LDS, B-in-registers 3-segment bf16 GEMM -------
#define GLD_LDS16(g, l)                                                  \
  __builtin_amdgcn_global_load_lds(                                      \
      (const __attribute__((address_space(1))) void*)(g),                \
      (__attribute__((address_space(3))) void*)(l), 16, 0, 0)

__global__ __launch_bounds__(512, 2) void gemm_pipe_kernel(
    const u16* __restrict__ Xhi, const u16* __restrict__ Xlo,
    const u16* __restrict__ Whi, const u16* __restrict__ Wlo,
    const float* __restrict__ bias, float* __restrict__ out) {
  // A only: 2 bufs x 256x64 bf16 = 2 x 32 KiB = 64 KiB.
  // unit = 16B chunk; row r slot s: unit = r*8+s; global chunk c of row r
  // lands at slot s = c ^ (r&7)  (conflict-free ds_read_b128; 0 in R3/R6).
  __shared__ __align__(16) u16 LDS[32768];

  const int t = threadIdx.x;
  const int lane = t & 63;
  const int wv = t >> 6;   // 0..7
  const int wm = wv >> 2;  // 0..1: 128-row half
  const int wn = wv & 3;   // 0..3: 64-col strip
  const int fr = lane & 15;
  const int fq = lane >> 4;

  // T1: XCD swizzle (bijective: 512 % 8 == 0), 64 contiguous wgs per XCD.
  const int wg = ((blockIdx.x & 7) << 6) | (blockIdx.x >> 3);
  const int m0 = (wg >> 4) * 256;  // 32 m-tiles
  const int n0 = (wg & 15) * 256;  // 16 n-tiles

  // A staging source: thread t stages dst unit (h*1024+q*512+t) <- global row
  // (h&1)*128 + q*64 + (t>>3), chunk (t&7)^((t>>3)&7).
  const int scol = ((t & 7) ^ ((t >> 3) & 7)) * 8;
  const size_t aoff = (size_t)(m0 + (t >> 3)) * IN_F + scol;

  // A ds_read lane offsets (u16): frag(row base R, kstep ks) at
  // (R+fr)*64 + ((ks*4+fq)^(fr&7))*8   (R%8==0 everywhere)
  const int lk0 = fr * 64 + (((0 * 4 + fq) ^ (fr & 7)) * 8);
  const int lk1 = fr * 64 + (((1 * 4 + fq) ^ (fr & 7)) * 8);

  // B global lane base: fragment (ni,ks) = 16B at
  // row (n0 + wn*64 + ni*16 + fr), k = k0 + ks*32 + fq*8.
  // Per wave the 64 lanes cover 16 rows x full 64B lines (line-efficient).
  const size_t bOff = (size_t)(n0 + wn * 64 + fr) * IN_F + fq * 8;

  f32x4 acc[8][4];  // [mh*4+mi][nh*2+ci]
#pragma unroll
  for (int i = 0; i < 8; ++i)
#pragma unroll
    for (int j = 0; j < 4; ++j) {
      acc[i][j][0] = 0.f; acc[i][j][1] = 0.f;
      acc[i][j][2] = 0.f; acc[i][j][3] = 0.f;
    }

  // segment g>>6: A from {Xhi,Xlo,Xhi}; B from {Whi,Whi,Wlo}
  auto stageA = [&](int g, int sbuf) {  // 4 gld_lds
    const int sg = g >> 6;
    const u16* ap = (sg == 1) ? Xlo : Xhi;
    const int k0 = (g & 63) << 6;
    u16* dA = (u16*)&LDS[sbuf * 16384];
    const u16* s = ap + aoff + k0;
    GLD_LDS16(s, dA + t * 8);
    GLD_LDS16(s + (size_t)64 * IN_F, dA + (512 + t) * 8);
    GLD_LDS16(s + (size_t)128 * IN_F, dA + (1024 + t) * 8);
    GLD_LDS16(s + (size_t)192 * IN_F, dA + (1536 + t) * 8);
  };
  auto loadB = [&](int g, u16x8 (&dst)[8]) {  // 8 global b128 -> regs
    const u16* bp = ((g >> 6) == 2) ? Wlo : Whi;
    const u16* s = bp + bOff + ((g & 63) << 6);
#pragma unroll
    for (int ni = 0; ni < 4; ++ni)
#pragma unroll
      for (int ks = 0; ks < 2; ++ks)
        dst[ni * 2 + ks] =
            *(const u16x8*)(s + (size_t)ni * 16 * IN_F + ks * 32);
  };

#define MFMA_Q(AIDX, BARR, BIDX, ACC)                                   \
  ACC = __builtin_amdgcn_mfma_f32_16x16x32_bf16(                        \
      __builtin_bit_cast(bf16x8, af[AIDX]),                             \
      __builtin_bit_cast(bf16x8, BARR[BIDX]), ACC, 0, 0, 0)

  u16x8 Bx[8], By[8];

  // prologue: tile 0's A into buf 0, B into Bx
  stageA(0, 0);
  loadB(0, Bx);

  // tile body: Bc = this tile's B (in regs), Bn = next tile's B (prefetch)
  auto tile = [&](int tt, u16x8 (&Bc)[8], u16x8 (&Bn)[8]) {
    const int buf = tt & 1;
    const u16* Ab = &LDS[buf * 16384];
    int g = tt + 1;
    if (g >= NT64) g = NT64 - 1;  // dummy re-load: uniform ledger
    const int sbuf = buf ^ 1;

    // stageA(tt)+loadB(tt) were issued a full tile ago: drain ~free.
    // barrier => all waves' A(tt) landed; all sbuf A-readers done.
    asm volatile("s_waitcnt vmcnt(0)" ::: "memory");
    __builtin_amdgcn_s_barrier();
    __builtin_amdgcn_sched_barrier(0);  // nothing hoists above the barrier

    u16x8 af[8];

    // ---- region 0: af(mh0) 8 ds_reads; prefetch B(t+1); stage A(t+1) ----
#pragma unroll
    for (int mi = 0; mi < 4; ++mi) {
      af[mi * 2 + 0] = *(const u16x8*)&Ab[wm * 8192 + mi * 1024 + lk0];
      af[mi * 2 + 1] = *(const u16x8*)&Ab[wm * 8192 + mi * 1024 + lk1];
    }
    loadB(g, Bn);
    stageA(g, sbuf);
    __builtin_amdgcn_sched_barrier(0);

    // ---- P0 (mh0 x nh0): Bc ready since last tile; af via counted lgkm ----
    __builtin_amdgcn_s_setprio(1);
#pragma unroll
    for (int mi = 0; mi < 4; ++mi)
#pragma unroll
      for (int ci = 0; ci < 2; ++ci) {
        MFMA_Q(mi * 2 + 0, Bc, ci * 2 + 0, acc[mi][ci]);
        MFMA_Q(mi * 2 + 1, Bc, ci * 2 + 1, acc[mi][ci]);
      }
    __builtin_amdgcn_s_setprio(0);
    __builtin_amdgcn_sched_barrier(0);

    // ---- P1 (mh0 x nh1) ----
    __builtin_amdgcn_s_setprio(1);
#pragma unroll
    for (int mi = 0; mi < 4; ++mi)
#pragma unroll
      for (int ci = 0; ci < 2; ++ci) {
        MFMA_Q(mi * 2 + 0, Bc, 4 + ci * 2 + 0, acc[mi][2 + ci]);
        MFMA_Q(mi * 2 + 1, Bc, 4 + ci * 2 + 1, acc[mi][2 + ci]);
      }
    __builtin_amdgcn_s_setprio(0);
    __builtin_amdgcn_sched_barrier(0);

    // ---- region 1: af <- mh1 (WAR on af: safe, MFMAs read at issue) ----
#pragma unroll
    for (int mi = 0; mi < 4; ++mi) {
      af[mi * 2 + 0] = *(const u16x8*)&Ab[wm * 8192 + 4096 + mi * 1024 + lk0];
      af[mi * 2 + 1] = *(const u16x8*)&Ab[wm * 8192 + 4096 + mi * 1024 + lk1];
    }
    __builtin_amdgcn_sched_barrier(0);

    // ---- P2 (mh1 x nh1) + P3 (mh1 x nh0) ----
    __builtin_amdgcn_s_setprio(1);
#pragma unroll
    for (int mi = 0; mi < 4; ++mi)
#pragma unroll
      for (int ci = 0; ci < 2; ++ci) {
        MFMA_Q(mi * 2 + 0, Bc, 4 + ci * 2 + 0, acc[4 + mi][2 + ci]);
        MFMA_Q(mi * 2 + 1, Bc, 4 + ci * 2 + 1, acc[4 + mi][2 + ci]);
      }
#pragma unroll
    for (int mi = 0; mi < 4; ++mi)
#pragma unroll
      for (int ci = 0; ci < 2; ++ci) {
        MFMA_Q(mi * 2 + 0, Bc, ci * 2 + 0, acc[4 + mi][ci]);
        MFMA_Q(mi * 2 + 1, Bc, ci * 2 + 1, acc[4 + mi][ci]);
      }
    __builtin_amdgcn_s_setprio(0);
    // no closing barrier: next tile-top vmcnt+barrier closes this tile
  };

#pragma unroll 1
  for (int p = 0; p < NT64 / 2; ++p) {
    tile(2 * p + 0, Bx, By);
    tile(2 * p + 1, By, Bx);
  }

  // epilogue: C/D layout col=lane&15, row=(lane>>4)*4+reg (R1/R3/R6 verified)
#pragma unroll
  for (int a = 0; a < 8; ++a) {
    const int row = m0 + wm * 128 + (a >> 2) * 64 + (a & 3) * 16 + fq * 4;
#pragma unroll
    for (int b = 0; b < 4; ++b) {
      const int col = n0 + wn * 64 + (b >> 1) * 32 + (b & 1) * 16 + fr;
      const float bb = bias[col];
#pragma unroll
      for (int r = 0; r < 4; ++r)
        out[(size_t)(row + r) * OUT_F + col] = acc[a][b][r] + bb;
    }
  }
#undef MFMA_Q
}

// -------- fallback (only if ws too small): fp32 vector GEMM, LoRA fused ----
__global__ __launch_bounds__(256) void gemm_f32_fallback(
    const float* __restrict__ X, const float* __restrict__ W,
    const float* __restrict__ lA, const float* __restrict__ lB,
    const float* __restrict__ bias, float* __restrict__ out) {
  __shared__ __align__(16) float Xs[64 * 32];
  __shared__ __align__(16) float Ws[64 * 32];
  const int t = threadIdx.x;
  const int bm = blockIdx.x & 127;
  const int bn = blockIdx.x >> 7;
  const int m0 = bm * 64, n0 = bn * 64;
  const int tx = t & 15, ty = t >> 4;
  float acc[4][4] = {};
  for (int k0 = 0; k0 < IN_F; k0 += 32) {
    __syncthreads();
#pragma unroll
    for (int q = 0; q < 2; ++q) {
      const int e4 = t * 2 + q;
      const int row = e4 >> 3;
      const int col = (e4 & 7) * 4;
      float4 xv = *(const float4*)(X + (size_t)(m0 + row) * IN_F + k0 + col);
      *(float4*)(Xs + row * 32 + col) = xv;
      float4 wv = *(const float4*)(W + (size_t)(n0 + row) * IN_F + k0 + col);
#pragma unroll
      for (int r = 0; r < RANK; ++r) {
        const float a = lA[(n0 + row) * RANK + r];
        const float4 b = *(const float4*)(lB + (size_t)r * IN_F + k0 + col);
        wv.x += a * b.x; wv.y += a * b.y; wv.z += a * b.z; wv.w += a * b.w;
      }
      *(float4*)(Ws + row * 32 + col) = wv;
    }
    __syncthreads();
#pragma unroll
    for (int kk = 0; kk < 32; ++kk) {
      float xr[4], wcol[4];
#pragma unroll
      for (int i = 0; i < 4; ++i) xr[i] = Xs[(ty * 4 + i) * 32 + kk];
#pragma unroll
      for (int j = 0; j < 4; ++j) wcol[j] = Ws[(tx * 4 + j) * 32 + kk];
#pragma unroll
      for (int i = 0; i < 4; ++i)
#pragma unroll
        for (int j = 0; j < 4; ++j) acc[i][j] += xr[i] * wcol[j];
    }
  }
#pragma unroll
  for (int i = 0; i < 4; ++i) {
    const int row = m0 + ty * 4 + i;
#pragma unroll
    for (int j = 0; j < 4; ++j) {
      const int col = n0 + tx * 4 + j;
      out[(size_t)row * OUT_F + col] = acc[i][j] + bias[col];
    }
  }
}

extern "C" void kernel_launch(void* const* d_in, const int* in_sizes, int n_in,
                              void* d_out, int out_size, void* d_ws,
                              size_t ws_size, hipStream_t stream) {
  const float* x    = (const float*)d_in[0];
  const float* W    = (const float*)d_in[1];
  const float* bias = (const float*)d_in[2];
  const float* lA   = (const float*)d_in[3];
  const float* lB   = (const float*)d_in[4];
  float* out = (float*)d_out;

  const size_t MK = (size_t)MTOT * IN_F;
  const size_t NK = (size_t)OUT_F * IN_F;
  const size_t need = (MK * 2 + NK * 2) * sizeof(u16);  // 192 MiB

  if (ws_size >= need) {
    u16* Xhi = (u16*)d_ws;
    u16* Xlo = Xhi + MK;
    u16* Whi = Xlo + MK;
    u16* Wlo = Whi + NK;
    prep_kernel<<<4096, 256, 0, stream>>>(x, W, lA, lB, Xhi, Xlo, Whi, Wlo);
    gemm_pipe_kernel<<<512, 512, 0, stream>>>(Xhi, Xlo, Whi, Wlo, bias, out);
  } else {
    gemm_f32_fallback<<<128 * 64, 256, 0, stream>>>(x, W, lA, lB, bias, out);
  }
}

// Round 9
// 1079.134 us; speedup vs baseline: 1.2184x; 1.2184x over previous
//
#include <hip/hip_runtime.h>
#include <hip/hip_bf16.h>
#include <stdint.h>

// LoRALinear fused: y = x @ (W + lora_A @ lora_B)^T + bias
// W_eff = W + A@B folded; x, W_eff split to bf16 hi+lo; 3-segment bf16 MFMA
// GEMM (hi*hi + lo*hi + hi*lo), fp32 accumulate. K_eff = 3*4096 = 12288.
// R9 GEMM = R7 schedule skeleton (BK=64 dbuf LDS, 1 barrier + 1 vmcnt(0)/tile,
// XOR swizzle, front-loaded ds_read issue, setprio MFMA clusters) with
// 32x32x16 MFMA fragments (2382 vs 2075 TF ubench: -13% MFMA floor, half the
// MFMA instruction count). B stays in LDS (R8's B-in-VGPR global gather was a
// TA-divergence disaster: 626->1133us, reverted).

typedef unsigned short u16;
typedef __attribute__((ext_vector_type(8))) u16 u16x8;
typedef __attribute__((ext_vector_type(4))) u16 u16x4;
typedef __attribute__((ext_vector_type(8))) __bf16 bf16x8;
typedef __attribute__((ext_vector_type(16))) float f32x16;

#define IN_F 4096
#define OUT_F 4096
#define MTOT 8192  // B*S
#define RANK 16
#define NT64 192  // 3 segments * (4096/64) K-tiles

__device__ __forceinline__ u16 f2bf(float f) {
  unsigned u = __float_as_uint(f);
  unsigned r = u + 0x7FFFu + ((u >> 16) & 1u);
  return (u16)(r >> 16);
}
__device__ __forceinline__ float bf2f(u16 h) {
  return __uint_as_float(((unsigned)h) << 16);
}

// ---------------- fused prep ----------------
// blocks [0,7168): x -> Xhi,Xlo (grid-stride).
// blocks [7168,8192): W_eff rows -> Whi,Wlo (lB held in registers).
__global__ __launch_bounds__(256) void prep_kernel(
    const float* __restrict__ x, const float* __restrict__ W,
    const float* __restrict__ lA, const float* __restrict__ lB,
    u16* __restrict__ xhi, u16* __restrict__ xlo, u16* __restrict__ whi,
    u16* __restrict__ wlo) {
  const int t = threadIdx.x;
  if (blockIdx.x < 7168) {
    const int n4 = (MTOT * IN_F) / 4;
    int idx = blockIdx.x * 256 + t;
    for (; idx < n4; idx += 7168 * 256) {
      float4 v = ((const float4*)x)[idx];
      u16x4 h, l;
      h.x = f2bf(v.x); l.x = f2bf(v.x - bf2f(h.x));
      h.y = f2bf(v.y); l.y = f2bf(v.y - bf2f(h.y));
      h.z = f2bf(v.z); l.z = f2bf(v.z - bf2f(h.z));
      h.w = f2bf(v.w); l.w = f2bf(v.w - bf2f(h.w));
      ((u16x4*)xhi)[idx] = h;
      ((u16x4*)xlo)[idx] = l;
    }
  } else {
    const int bw = blockIdx.x - 7168;
    const int strip = bw & 31;
    const int og = bw >> 5;
    const int i4 = strip * 32 + (t & 31);
    float4 lbr[RANK];
#pragma unroll
    for (int r = 0; r < RANK; ++r)
      lbr[r] = ((const float4*)lB)[r * (IN_F / 4) + i4];
#pragma unroll 1
    for (int j = 0; j < 16; ++j) {
      const int o = og * 128 + (t >> 5) + 8 * j;
      float a[RANK];
#pragma unroll
      for (int q = 0; q < 4; ++q) {
        float4 av = ((const float4*)lA)[o * (RANK / 4) + q];
        a[q * 4 + 0] = av.x; a[q * 4 + 1] = av.y;
        a[q * 4 + 2] = av.z; a[q * 4 + 3] = av.w;
      }
      float4 acc = ((const float4*)W)[o * (IN_F / 4) + i4];
#pragma unroll
      for (int r = 0; r < RANK; ++r) {
        acc.x += a[r] * lbr[r].x; acc.y += a[r] * lbr[r].y;
        acc.z += a[r] * lbr[r].z; acc.w += a[r] * lbr[r].w;
      }
      u16x4 h, l;
      h.x = f2bf(acc.x); l.x = f2bf(acc.x - bf2f(h.x));
      h.y = f2bf(acc.y); l.y = f2bf(acc.y - bf2f(h.y));
      h.z = f2bf(acc.z); l.z = f2bf(acc.z - bf2f(h.z));
      h.w = f2bf(acc.w); l.w = f2bf(acc.w - bf2f(h.w));
      ((u16x4*)whi)[o * (IN_F / 4) + i4] = h;
      ((u16x4*)wlo)[o * (IN_F / 4) + i4] = l;
    }
  }
}

// ---------------- main: BK=64, 32x32x16-MFMA 3-segment bf16 GEMM -----------
#define GLD_LDS16(g, l)                                                  \
  __builtin_amdgcn_global_load_lds(                                      \
      (const __attribute__((address_space(1))) void*)(g),                \
      (__attribute__((address_space(3))) void*)(l), 16, 0, 0)

__global__ __launch_bounds__(512, 2) void gemm_pipe_kernel(
    const u16* __restrict__ Xhi, const u16* __restrict__ Xlo,
    const u16* __restrict__ Whi, const u16* __restrict__ Wlo,
    const float* __restrict__ bias, float* __restrict__ out) {
  // 2 bufs x (A 256x64 | B 256x64) bf16 = 2 x 64 KiB = 128 KiB.
  // unit = 16B chunk; row r slot s: unit = r*8+s; global chunk c of row r
  // lands at slot s = c ^ (r&7)  (conflict-free ds_read_b128; 0 in R3/R6/R7).
  __shared__ __align__(16) u16 LDS[65536];

  const int t = threadIdx.x;
  const int lane = t & 63;
  const int wv = t >> 6;   // 0..7
  const int wm = wv >> 2;  // 0..1: 128-row half
  const int wn = wv & 3;   // 0..3: 64-col strip
  const int rl = lane & 31;  // 32x32 fragment row/col
  const int kb = lane >> 5;  // k-block (8 elems)

  // T1: XCD swizzle (bijective: 512 % 8 == 0), 64 contiguous wgs per XCD.
  const int wg = ((blockIdx.x & 7) << 6) | (blockIdx.x >> 3);
  const int m0 = (wg >> 4) * 256;  // 32 m-tiles
  const int n0 = (wg & 15) * 256;  // 16 n-tiles

  // staging source: thread t stages dst unit (h*1024+q*512+t) <- global row
  // (h&1)*128 + q*64 + (t>>3), chunk (t&7)^((t>>3)&7).  (unchanged from R6)
  const int scol = ((t & 7) ^ ((t >> 3) & 7)) * 8;
  const size_t aoff = (size_t)(m0 + (t >> 3)) * IN_F + scol;
  const size_t boff = (size_t)(n0 + (t >> 3)) * IN_F + scol;

  // 32x32x16 operand layout: lane holds row rl, k = ks*16 + kb*8 .. +7
  // -> chunk c = ks*2 + kb; u16 offset = (R+rl)*64 + ((c ^ (rl&7))*8),
  // R%32==0 so (row&7) == (rl&7). Octet bank-groups all-distinct.
  int lkk[4];
#pragma unroll
  for (int ks = 0; ks < 4; ++ks)
    lkk[ks] = rl * 64 + (((ks * 2 + kb) ^ (rl & 7)) * 8);

  f32x16 acc[4][2];  // [mi][ci]: out rows mi*32+.., cols ci*32+..
#pragma unroll
  for (int i = 0; i < 4; ++i)
#pragma unroll
    for (int j = 0; j < 2; ++j)
#pragma unroll
      for (int k = 0; k < 16; ++k) acc[i][j][k] = 0.f;

  // segment g>>6: A from {Xhi,Xlo,Xhi}; B from {Whi,Whi,Wlo}
  auto stageA = [&](int g, int sbuf) {  // 4 gld_lds
    const int sg = g >> 6;
    const u16* ap = (sg == 1) ? Xlo : Xhi;
    const int k0 = (g & 63) << 6;
    u16* dA = (u16*)&LDS[sbuf * 32768];
    const u16* s = ap + aoff + k0;
    GLD_LDS16(s, dA + t * 8);
    GLD_LDS16(s + (size_t)64 * IN_F, dA + (512 + t) * 8);
    GLD_LDS16(s + (size_t)128 * IN_F, dA + (1024 + t) * 8);
    GLD_LDS16(s + (size_t)192 * IN_F, dA + (1536 + t) * 8);
  };
  auto stageB = [&](int g, int sbuf) {  // 4 gld_lds
    const int sg = g >> 6;
    const u16* bp = (sg == 2) ? Wlo : Whi;
    const int k0 = (g & 63) << 6;
    u16* dB = (u16*)&LDS[sbuf * 32768 + 16384];
    const u16* s = bp + boff + k0;
    GLD_LDS16(s, dB + t * 8);
    GLD_LDS16(s + (size_t)64 * IN_F, dB + (512 + t) * 8);
    GLD_LDS16(s + (size_t)128 * IN_F, dB + (1024 + t) * 8);
    GLD_LDS16(s + (size_t)192 * IN_F, dB + (1536 + t) * 8);
  };

#define MFMA32(AARR, AIDX, BARR, BIDX, ACC)                             \
  ACC = __builtin_amdgcn_mfma_f32_32x32x16_bf16(                        \
      __builtin_bit_cast(bf16x8, AARR[AIDX]),                           \
      __builtin_bit_cast(bf16x8, BARR[BIDX]), ACC, 0, 0, 0)

  // prologue: stage tile 0 into buf 0 (8 loads)
  stageA(0, 0); stageB(0, 0);

#pragma unroll 1
  for (int tt = 0; tt < NT64; ++tt) {
    const int buf = tt & 1;
    const u16* Ab = &LDS[buf * 32768];
    const u16* Bb = Ab + 16384;
    int g = tt + 1;
    if (g >= NT64) g = NT64 - 1;  // dummy re-stage: uniform vmcnt ledger
    const int sbuf = buf ^ 1;

    // tile-tt loads were issued >=2 phases ago: drain ~free.
    // barrier => all waves' tile-tt loads landed; all sbuf readers done.
    asm volatile("s_waitcnt vmcnt(0)" ::: "memory");
    __builtin_amdgcn_s_barrier();
    __builtin_amdgcn_sched_barrier(0);  // nothing hoists above the barrier

    u16x8 af[8], af2[8], bf0[4], bf1[4];

    // ---- region 0: issue af(mi0,1) 8 + bf0 4 + bf1 4; stage A(t+1) ----
#pragma unroll
    for (int mi = 0; mi < 2; ++mi)
#pragma unroll
      for (int ks = 0; ks < 4; ++ks)
        af[mi * 4 + ks] =
            *(const u16x8*)&Ab[wm * 8192 + mi * 2048 + lkk[ks]];
#pragma unroll
    for (int ks = 0; ks < 4; ++ks) {
      bf0[ks] = *(const u16x8*)&Bb[wn * 4096 + lkk[ks]];
      bf1[ks] = *(const u16x8*)&Bb[wn * 4096 + 2048 + lkk[ks]];
    }
    stageA(g, sbuf);
    __builtin_amdgcn_sched_barrier(0);

    // ---- P0 (mi0,1 x ci0): compiler-counted lgkm waits ----
    __builtin_amdgcn_s_setprio(1);
#pragma unroll
    for (int ks = 0; ks < 4; ++ks)
#pragma unroll
      for (int mi = 0; mi < 2; ++mi)
        MFMA32(af, mi * 4 + ks, bf0, ks, acc[mi][0]);
    __builtin_amdgcn_s_setprio(0);
    __builtin_amdgcn_sched_barrier(0);

    // ---- region 1: issue af2(mi2,3) 8 (overlaps P1); stage B(t+1) ----
#pragma unroll
    for (int mi = 0; mi < 2; ++mi)
#pragma unroll
      for (int ks = 0; ks < 4; ++ks)
        af2[mi * 4 + ks] =
            *(const u16x8*)&Ab[wm * 8192 + (2 + mi) * 2048 + lkk[ks]];
    stageB(g, sbuf);
    __builtin_amdgcn_sched_barrier(0);

    // ---- P1 (mi0,1 x ci1) ----
    __builtin_amdgcn_s_setprio(1);
#pragma unroll
    for (int ks = 0; ks < 4; ++ks)
#pragma unroll
      for (int mi = 0; mi < 2; ++mi)
        MFMA32(af, mi * 4 + ks, bf1, ks, acc[mi][1]);
    __builtin_amdgcn_s_setprio(0);
    __builtin_amdgcn_sched_barrier(0);

    // ---- P2 (mi2,3 x ci1) + P3 (mi2,3 x ci0) ----
    __builtin_amdgcn_s_setprio(1);
#pragma unroll
    for (int ks = 0; ks < 4; ++ks)
#pragma unroll
      for (int mi = 0; mi < 2; ++mi)
        MFMA32(af2, mi * 4 + ks, bf1, ks, acc[2 + mi][1]);
#pragma unroll
    for (int ks = 0; ks < 4; ++ks)
#pragma unroll
      for (int mi = 0; mi < 2; ++mi)
        MFMA32(af2, mi * 4 + ks, bf0, ks, acc[2 + mi][0]);
    __builtin_amdgcn_s_setprio(0);
    // no closing barrier: next tile-top vmcnt+barrier closes this tile
  }

  // epilogue: 32x32 C/D layout col=lane&31, row=(reg&3)+8*(reg>>2)+4*(lane>>5)
  // (m74/m101 verified)
#pragma unroll
  for (int mi = 0; mi < 4; ++mi)
#pragma unroll
    for (int ci = 0; ci < 2; ++ci) {
      const int col = n0 + wn * 64 + ci * 32 + rl;
      const float bb = bias[col];
#pragma unroll
      for (int reg = 0; reg < 16; ++reg) {
        const int row =
            m0 + wm * 128 + mi * 32 + (reg & 3) + 8 * (reg >> 2) + 4 * kb;
        out[(size_t)row * OUT_F + col] = acc[mi][ci][reg] + bb;
      }
    }
#undef MFMA32
}

// -------- fallback (only if ws too small): fp32 vector GEMM, LoRA fused ----
__global__ __launch_bounds__(256) void gemm_f32_fallback(
    const float* __restrict__ X, const float* __restrict__ W,
    const float* __restrict__ lA, const float* __restrict__ lB,
    const float* __restrict__ bias, float* __restrict__ out) {
  __shared__ __align__(16) float Xs[64 * 32];
  __shared__ __align__(16) float Ws[64 * 32];
  const int t = threadIdx.x;
  const int bm = blockIdx.x & 127;
  const int bn = blockIdx.x >> 7;
  const int m0 = bm * 64, n0 = bn * 64;
  const int tx = t & 15, ty = t >> 4;
  float acc[4][4] = {};
  for (int k0 = 0; k0 < IN_F; k0 += 32) {
    __syncthreads();
#pragma unroll
    for (int q = 0; q < 2; ++q) {
      const int e4 = t * 2 + q;
      const int row = e4 >> 3;
      const int col = (e4 & 7) * 4;
      float4 xv = *(const float4*)(X + (size_t)(m0 + row) * IN_F + k0 + col);
      *(float4*)(Xs + row * 32 + col) = xv;
      float4 wv = *(const float4*)(W + (size_t)(n0 + row) * IN_F + k0 + col);
#pragma unroll
      for (int r = 0; r < RANK; ++r) {
        const float a = lA[(n0 + row) * RANK + r];
        const float4 b = *(const float4*)(lB + (size_t)r * IN_F + k0 + col);
        wv.x += a * b.x; wv.y += a * b.y; wv.z += a * b.z; wv.w += a * b.w;
      }
      *(float4*)(Ws + row * 32 + col) = wv;
    }
    __syncthreads();
#pragma unroll
    for (int kk = 0; kk < 32; ++kk) {
      float xr[4], wcol[4];
#pragma unroll
      for (int i = 0; i < 4; ++i) xr[i] = Xs[(ty * 4 + i) * 32 + kk];
#pragma unroll
      for (int j = 0; j < 4; ++j) wcol[j] = Ws[(tx * 4 + j) * 32 + kk];
#pragma unroll
      for (int i = 0; i < 4; ++i)
#pragma unroll
        for (int j = 0; j < 4; ++j) acc[i][j] += xr[i] * wcol[j];
    }
  }
#pragma unroll
  for (int i = 0; i < 4; ++i) {
    const int row = m0 + ty * 4 + i;
#pragma unroll
    for (int j = 0; j < 4; ++j) {
      const int col = n0 + tx * 4 + j;
      out[(size_t)row * OUT_F + col] = acc[i][j] + bias[col];
    }
  }
}

extern "C" void kernel_launch(void* const* d_in, const int* in_sizes, int n_in,
                              void* d_out, int out_size, void* d_ws,
                              size_t ws_size, hipStream_t stream) {
  const float* x    = (const float*)d_in[0];
  const float* W    = (const float*)d_in[1];
  const float* bias = (const float*)d_in[2];
  const float* lA   = (const float*)d_in[3];
  const float* lB   = (const float*)d_in[4];
  float* out = (float*)d_out;

  const size_t MK = (size_t)MTOT * IN_F;
  const size_t NK = (size_t)OUT_F * IN_F;
  const size_t need = (MK * 2 + NK * 2) * sizeof(u16);  // 192 MiB

  if (ws_size >= need) {
    u16* Xhi = (u16*)d_ws;
    u16* Xlo = Xhi + MK;
    u16* Whi = Xlo + MK;
    u16* Wlo = Whi + NK;
    prep_kernel<<<8192, 256, 0, stream>>>(x, W, lA, lB, Xhi, Xlo, Whi, Wlo);
    gemm_pipe_kernel<<<512, 512, 0, stream>>>(Xhi, Xlo, Whi, Wlo, bias, out);
  } else {
    gemm_f32_fallback<<<128 * 64, 256, 0, stream>>>(x, W, lA, lB, bias, out);
  }
}